// Round 2
// baseline (1534.294 us; speedup 1.0000x reference)
//
#include <hip/hip_runtime.h>
#include <hip/hip_bf16.h>
#include <math.h>

#define L_SEQ 6464
#define NSITE_ 101
#define NCELL_ 64
#define DM 64
#define DI 128
#define DS 16
#define CHUNK 101
#define NCH 64

// ---------------- prologue: concat + pos, then @W_fcc + b_fcc ----------------
__global__ void k_embed(const float* __restrict__ DNA, const float* __restrict__ CpG,
                        const float* __restrict__ cell, const float* __restrict__ pos,
                        const float* __restrict__ Wfcc, const float* __restrict__ bfcc,
                        float* __restrict__ x0) {
    int l = blockIdx.x;
    int j = threadIdx.x;  // 64
    __shared__ float in64[64];
    float v;
    if (j < 16)       v = CpG[l * 16 + j];
    else if (j < 32)  v = cell[l * 16 + (j - 16)];
    else              v = DNA[l * 32 + (j - 32)];
    v += pos[l * 64 + j];
    in64[j] = v;
    __syncthreads();
    float acc = bfcc[j];
    for (int i = 0; i < 64; i++) acc += in64[i] * Wfcc[i * 64 + j];
    x0[(size_t)l * 64 + j] = acc;
}

// ---------------- xz = x @ W_in  (L x 64 @ 64 x 256) ----------------
__global__ void k_gemm_in(const float* __restrict__ x, const float* __restrict__ Win,
                          float* __restrict__ xz) {
    int l = blockIdx.x;
    int j = threadIdx.x;  // 256
    __shared__ float xr[64];
    if (j < 64) xr[j] = x[(size_t)l * 64 + j];
    __syncthreads();
    float acc = 0.f;
    for (int i = 0; i < 64; i++) acc += xr[i] * Win[i * 256 + j];
    xz[(size_t)l * 256 + j] = acc;
}

// ---------------- depthwise causal conv + silu, both directions ----------------
__global__ void k_conv(const float* __restrict__ xz, const float* __restrict__ convw,
                       const float* __restrict__ convb, float* __restrict__ xc) {
    int idx = blockIdx.x * blockDim.x + threadIdx.x;
    if (idx >= 2 * L_SEQ * DI) return;
    int d = idx & 127;
    int l = (idx >> 7) % L_SEQ;
    int dir = idx / (L_SEQ * DI);
    float acc = convb[d];
    if (dir == 0) {
        for (int k = 0; k < 4; k++) {
            int r = l - 3 + k;
            if (r >= 0) acc += convw[d * 4 + k] * xz[(size_t)r * 256 + d];
        }
    } else {
        for (int k = 0; k < 4; k++) {
            int r = l + 3 - k;
            if (r < L_SEQ) acc += convw[d * 4 + k] * xz[(size_t)r * 256 + d];
        }
    }
    xc[idx] = acc / (1.f + expf(-acc));  // silu
}

// ---------------- xdbl = xc @ W_xp ; dt = softplus(xdbl[:,:4]@W_dt + b_dt) ----------------
__global__ void k_xp_dt(const float* __restrict__ xc, const float* __restrict__ Wxp,
                        const float* __restrict__ Wdt, const float* __restrict__ bdt,
                        float* __restrict__ dt, float* __restrict__ BC) {
    int blk = blockIdx.x;             // 2*L
    int dir = blk / L_SEQ;
    int l = blk % L_SEQ;
    int t = threadIdx.x;              // 128
    const float* xcrow = xc + (size_t)(dir * L_SEQ + l) * DI;
    __shared__ float xr[128];
    __shared__ float xd[36];
    xr[t] = xcrow[t];
    __syncthreads();
    if (t < 36) {
        float acc = 0.f;
        for (int i = 0; i < 128; i++) acc += xr[i] * Wxp[i * 36 + t];
        xd[t] = acc;
    }
    __syncthreads();
    float pre = bdt[t];
    for (int r = 0; r < 4; r++) pre += xd[r] * Wdt[r * 128 + t];
    float dtv = (pre > 20.f) ? pre : log1pf(expf(pre));
    dt[(size_t)(dir * L_SEQ + l) * DI + t] = dtv;
    if (t < 32) BC[(size_t)(dir * L_SEQ + l) * 32 + t] = xd[4 + t];
}

// ---------------- scan phase 1: per-chunk (prod a, local scan end) ----------------
__global__ void k_scan1(const float* __restrict__ dt, const float* __restrict__ xc,
                        const float* __restrict__ BC, const float* __restrict__ Alog,
                        float* __restrict__ carryA, float* __restrict__ carryB) {
    int s = threadIdx.x & 15;
    int dl = threadIdx.x >> 4;        // 16 d per block
    int d = blockIdx.x * 16 + dl;
    int c = blockIdx.y;
    int dir = blockIdx.z;
    float A = -expf(Alog[d * 16 + s]);
    const float* dtp = dt + (size_t)dir * L_SEQ * DI;
    const float* xcp = xc + (size_t)dir * L_SEQ * DI;
    const float* bcp = BC + (size_t)dir * L_SEQ * 32;
    float Ap = 1.f, h = 0.f;
    int t0 = c * CHUNK;
    for (int tl = 0; tl < CHUNK; tl++) {
        int t = t0 + tl;
        int row = dir ? (L_SEQ - 1 - t) : t;
        float dtv = dtp[(size_t)row * DI + d];
        float a = expf(dtv * A);
        float b = dtv * xcp[(size_t)row * DI + d] * bcp[(size_t)row * 32 + s];
        h = a * h + b;
        Ap *= a;
    }
    size_t o = ((size_t)dir * NCH + c) * 2048 + d * 16 + s;
    carryA[o] = Ap;
    carryB[o] = h;
}

// ---------------- scan phase 2: serial chunk combine ----------------
__global__ void k_scan2(const float* __restrict__ carryA, const float* __restrict__ carryB,
                        float* __restrict__ Hinit) {
    int idx = blockIdx.x * blockDim.x + threadIdx.x;  // 4096
    if (idx >= 2 * 2048) return;
    int dir = idx / 2048;
    int ds = idx % 2048;
    float h = 0.f;
    for (int c = 0; c < NCH; c++) {
        size_t o = ((size_t)dir * NCH + c) * 2048 + ds;
        Hinit[o] = h;
        h = carryA[o] * h + carryB[o];
    }
}

// ---------------- scan phase 3: replay with carry-in, contract with C, g = y*silu(z) ----------------
__global__ void k_scan3(const float* __restrict__ dt, const float* __restrict__ xc,
                        const float* __restrict__ BC, const float* __restrict__ xz,
                        const float* __restrict__ Alog, const float* __restrict__ Dres,
                        const float* __restrict__ Hinit, float* __restrict__ g) {
    int s = threadIdx.x & 15;
    int dl = threadIdx.x >> 4;
    int d = blockIdx.x * 16 + dl;
    int c = blockIdx.y;
    int dir = blockIdx.z;
    float A = -expf(Alog[d * 16 + s]);
    const float* dtp = dt + (size_t)dir * L_SEQ * DI;
    const float* xcp = xc + (size_t)dir * L_SEQ * DI;
    const float* bcp = BC + (size_t)dir * L_SEQ * 32;
    float* gp = g + (size_t)dir * L_SEQ * DI;
    float h = Hinit[((size_t)dir * NCH + c) * 2048 + d * 16 + s];
    float Dv = Dres[d];
    int t0 = c * CHUNK;
    for (int tl = 0; tl < CHUNK; tl++) {
        int t = t0 + tl;
        int row = dir ? (L_SEQ - 1 - t) : t;
        float dtv = dtp[(size_t)row * DI + d];
        float xcv = xcp[(size_t)row * DI + d];
        float a = expf(dtv * A);
        float b = dtv * xcv * bcp[(size_t)row * 32 + s];
        h = a * h + b;
        float val = h * bcp[(size_t)row * 32 + 16 + s];
        val += __shfl_xor(val, 1);
        val += __shfl_xor(val, 2);
        val += __shfl_xor(val, 4);
        val += __shfl_xor(val, 8);
        if (s == 0) {
            float y = val + xcv * Dv;
            float z = xz[(size_t)row * 256 + 128 + d];
            float sz = z / (1.f + expf(-z));
            gp[(size_t)row * DI + d] = y * sz;
        }
    }
}

// ---------------- out-GEMM + residual + layernorm + transpose-permute ----------------
__global__ void k_outln(const float* __restrict__ x, const float* __restrict__ g,
                        const float* __restrict__ Wout, const float* __restrict__ lng,
                        const float* __restrict__ lnb, float* __restrict__ xnext,
                        int permMode) {
    int l = blockIdx.x;
    int j = threadIdx.x;  // 64 (one wave)
    __shared__ float gs[128];
    gs[j] = 0.5f * (g[(size_t)l * 128 + j] + g[(size_t)(L_SEQ + l) * 128 + j]);
    gs[j + 64] = 0.5f * (g[(size_t)l * 128 + 64 + j] + g[(size_t)(L_SEQ + l) * 128 + 64 + j]);
    __syncthreads();
    float acc = x[(size_t)l * 64 + j];
    for (int i = 0; i < 128; i++) acc += gs[i] * Wout[i * 64 + j];
    // layernorm across the 64 lanes (single wave)
    float m = acc;
    for (int o = 32; o >= 1; o >>= 1) m += __shfl_xor(m, o);
    m *= (1.f / 64.f);
    float dv = acc - m;
    float v = dv * dv;
    for (int o = 32; o >= 1; o >>= 1) v += __shfl_xor(v, o);
    v *= (1.f / 64.f);
    float out = dv * rsqrtf(v + 1e-5f) * lng[j] + lnb[j];
    int l2;
    if (permMode == 0) l2 = (l % 64) * 101 + (l / 64);   // (s,c)->(c,s)
    else               l2 = (l % 101) * 64 + (l / 101);  // (c,s)->(s,c)
    xnext[(size_t)l2 * 64 + j] = out;
}

// ---------------- epilogue: @W_fc, select, sigmoid, 1-|y_true - s| ----------------
__global__ void k_epilogue(const float* __restrict__ x, const float* __restrict__ Wfc,
                           const float* __restrict__ bfc, const float* __restrict__ ytrue,
                           const int* __restrict__ halfwin, const int* __restrict__ rows,
                           float* __restrict__ out) {
    int k = threadIdx.x;  // 64
    int hw = halfwin[0];
    int c = rows[k];
    const float* xr = x + ((size_t)hw * 64 + c) * 64;
    float acc = bfc[0];
    for (int i = 0; i < 64; i++) acc += xr[i] * Wfc[i];
    float s = 1.f / (1.f + expf(-acc));
    float r = 1.f - fabsf(ytrue[k] - s);
    out[k] = r;
}

extern "C" void kernel_launch(void* const* d_in, const int* in_sizes, int n_in,
                              void* d_out, int out_size, void* d_ws, size_t ws_size,
                              hipStream_t stream) {
    const float* DNA   = (const float*)d_in[0];
    const float* CpG   = (const float*)d_in[1];
    const float* cel   = (const float*)d_in[2];
    const float* pos   = (const float*)d_in[3];
    const float* ytrue = (const float*)d_in[4];
    const float* Wfcc  = (const float*)d_in[5];
    const float* bfcc  = (const float*)d_in[6];
    const float* Win   = (const float*)d_in[7];
    const float* convw = (const float*)d_in[8];
    const float* convb = (const float*)d_in[9];
    const float* Wxp   = (const float*)d_in[10];
    const float* Wdt   = (const float*)d_in[11];
    const float* bdt   = (const float*)d_in[12];
    const float* Alog  = (const float*)d_in[13];
    const float* Dres  = (const float*)d_in[14];
    const float* Wout  = (const float*)d_in[15];
    const float* lng   = (const float*)d_in[16];
    const float* lnb   = (const float*)d_in[17];
    const float* Wfc   = (const float*)d_in[18];
    const float* bfc   = (const float*)d_in[19];
    const int* halfwin = (const int*)d_in[20];
    const int* rows    = (const int*)d_in[21];

    float* ws = (float*)d_ws;
    size_t off = 0;
    float* x0 = ws + off; off += (size_t)L_SEQ * 64;
    float* x1 = ws + off; off += (size_t)L_SEQ * 64;
    float* xz = ws + off; off += (size_t)L_SEQ * 256;
    float* xc = ws + off; off += (size_t)2 * L_SEQ * 128;
    float* dt = ws + off; off += (size_t)2 * L_SEQ * 128;
    float* BC = ws + off; off += (size_t)2 * L_SEQ * 32;
    float* g  = ws + off; off += (size_t)2 * L_SEQ * 128;
    float* cA = ws + off; off += (size_t)2 * NCH * 2048;
    float* cB = ws + off; off += (size_t)2 * NCH * 2048;
    float* Hi = ws + off; off += (size_t)2 * NCH * 2048;

    k_embed<<<L_SEQ, 64, 0, stream>>>(DNA, CpG, cel, pos, Wfcc, bfcc, x0);

    float* xcur = x0;
    float* xnxt = x1;
    for (int sb = 0; sb < 8; sb++) {
        k_gemm_in<<<L_SEQ, 256, 0, stream>>>(xcur, Win, xz);
        k_conv<<<(2 * L_SEQ * DI + 255) / 256, 256, 0, stream>>>(xz, convw, convb, xc);
        k_xp_dt<<<2 * L_SEQ, 128, 0, stream>>>(xc, Wxp, Wdt, bdt, dt, BC);
        k_scan1<<<dim3(8, NCH, 2), 256, 0, stream>>>(dt, xc, BC, Alog, cA, cB);
        k_scan2<<<16, 256, 0, stream>>>(cA, cB, Hi);
        k_scan3<<<dim3(8, NCH, 2), 256, 0, stream>>>(dt, xc, BC, xz, Alog, Dres, Hi, g);
        k_outln<<<L_SEQ, 64, 0, stream>>>(xcur, g, Wout, lng, lnb, xnxt, (sb % 2 == 0) ? 0 : 1);
        float* tmp = xcur; xcur = xnxt; xnxt = tmp;
    }

    k_epilogue<<<1, 64, 0, stream>>>(xcur, Wfc, bfc, ytrue, halfwin, rows, (float*)d_out);
}